// Round 6
// baseline (61.617 us; speedup 1.0000x reference)
//
#include <hip/hip_runtime.h>
#include <hip/hip_bf16.h>

// Problem constants (reference: N=768, D_IN=308, H=100, iterations=1)
// Inputs f32, output f32 (verified round 4). hh==0 on the single iteration,
// so B_W[500:600], B2_Wh, D_W/b are dead.
#define NW   768
#define HID  100
#define DIN  308
#define RPB  2          // rows per block in k_uu / k_fused
#define TJ   64         // pair-tile edge

typedef const float* fp;

// ---------------------------------------------------------------------------
// K0: probe integer-tensor storage (verified round 4).
// modes[0] (nf):  0=int32/word, 1=packed uint8, 2=int64
// modes[1] (idx): 0=int32, 1=int64
// ---------------------------------------------------------------------------
__global__ __launch_bounds__(192) void k_probe(const int* __restrict__ nf,
                                               const int* __restrict__ idx,
                                               int* __restrict__ modes) {
    __shared__ int bigNF, badNF, oddNF, evenNF, oddIX, evenIX;
    if (threadIdx.x == 0) { bigNF = badNF = oddNF = evenNF = oddIX = evenIX = 0; }
    __syncthreads();
    const int t = threadIdx.x;
    const unsigned vn = (unsigned)nf[t];
    if (vn > 1u) atomicOr(&bigNF, 1);
    if (vn & 0xFEFEFEFEu) atomicOr(&badNF, 1);
    if ((t & 1) && vn) atomicOr(&oddNF, 1);
    if (!(t & 1) && vn) atomicOr(&evenNF, 1);
    const unsigned vi = (unsigned)idx[t];
    if ((t & 1) && vi) atomicOr(&oddIX, 1);
    if (!(t & 1) && vi) atomicOr(&evenIX, 1);
    __syncthreads();
    if (t == 0) {
        int m = 0;
        if (!badNF && bigNF) m = 1;
        else if (!oddNF && evenNF) m = 2;
        modes[0] = m;
        modes[1] = (!oddIX && evenIX) ? 1 : 0;
    }
}

// ---------------------------------------------------------------------------
// K1: uu = tanh(vv @ A_W + A_b).  RPB rows/block, 512 thr = 4 k-slices x 128
// cols, LDS partial reduce. (unchanged from round 5)
// ---------------------------------------------------------------------------
__global__ __launch_bounds__(512) void k_uu(fp vv, fp A_W, fp A_b,
                                            float* __restrict__ uu) {
    __shared__ float vs[RPB][DIN];
    __shared__ float part[4][RPB][128];
    const int i0 = blockIdx.x * RPB;
    for (int t = threadIdx.x; t < RPB * DIN; t += 512) {
        const int r = t / DIN, k = t % DIN;
        vs[r][k] = vv[(i0 + r) * DIN + k];
    }
    __syncthreads();
    const int c = threadIdx.x & 127;
    const int s = threadIdx.x >> 7;
    float a0 = 0.f, a1 = 0.f;
    if (c < HID) {
        const int k0 = s * 77;
#pragma unroll 11
        for (int k = k0; k < k0 + 77; ++k) {
            const float w = A_W[k * HID + c];
            a0 = fmaf(vs[0][k], w, a0);
            a1 = fmaf(vs[1][k], w, a1);
        }
    }
    part[s][0][c] = a0; part[s][1][c] = a1;
    __syncthreads();
    for (int t = threadIdx.x; t < RPB * HID; t += 512) {
        const int r = t / HID, cc = t % HID;
        float acc = A_b[cc];
#pragma unroll
        for (int s2 = 0; s2 < 4; ++s2) acc += part[s2][r][cc];
        uu[(i0 + r) * HID + cc] = tanhf(acc);
    }
}

// ---------------------------------------------------------------------------
// K2 (fused): gather ww -> bb -> oo -> hl/hr for 3 heads.
// Same as round 5 EXCEPT the W1-stage now writes hlhr TRANSPOSED:
//   hlhrT[ho][k][row]   (k-major panels so k_pair can stage coalesced)
// ---------------------------------------------------------------------------
__global__ __launch_bounds__(640) void k_fused(
    const float* __restrict__ uu, const int* __restrict__ indices,
    const int* __restrict__ nf, const int* __restrict__ modes,
    fp B_W, fp B_b, fp B2_Wo, fp B2_bo,
    fp W1r, fp b1r, fp W1c, fp b1c, fp W1e, fp b1e,
    float* __restrict__ hlhrT) {
    __shared__ float ww[RPB][5 * HID];
    __shared__ float part[5][RPB][128];
    __shared__ float bbs[RPB][HID];
    __shared__ float oos[RPB][HID];
    const int i0 = blockIdx.x * RPB;
    const int mnf = modes[0], midx = modes[1];

    for (int t = threadIdx.x; t < RPB * 5 * HID; t += 640) {
        const int r = t / (5 * HID), u = t % (5 * HID);
        const int i = i0 + r;
        const bool notf = (mnf == 1) ? (((const unsigned char*)nf)[i] != 0)
                        : (mnf == 2) ? (nf[2 * i] != 0)
                                     : (nf[i] != 0);
        const int q = u / HID, cc = u % HID;
        int j = midx ? indices[2 * (i * 5 + q)] : indices[i * 5 + q];
        j = (j < 0) ? 0 : ((j >= NW) ? NW - 1 : j);
        ww[r][u] = notf ? 0.f : uu[j * HID + cc];
    }
    __syncthreads();

    const int c = threadIdx.x % 128;
    const int s = threadIdx.x / 128;

    {   // B-stage: k-slice of 100
        float a0 = 0.f, a1 = 0.f;
        if (c < HID) {
            const int k0 = s * 100;
#pragma unroll 10
            for (int k = k0; k < k0 + 100; ++k) {
                const float w = B_W[k * HID + c];
                a0 = fmaf(ww[0][k], w, a0);
                a1 = fmaf(ww[1][k], w, a1);
            }
        }
        part[s][0][c] = a0; part[s][1][c] = a1;
    }
    __syncthreads();
    for (int t = threadIdx.x; t < RPB * HID; t += 640) {
        const int r = t / HID, cc = t % HID;
        float acc = B_b[cc];
#pragma unroll
        for (int s2 = 0; s2 < 5; ++s2) acc += part[s2][r][cc];
        bbs[r][cc] = tanhf(acc);
    }
    __syncthreads();

    {   // oo-stage: k-slice of 20
        float a0 = 0.f, a1 = 0.f;
        if (c < HID) {
            const int k0 = s * 20;
#pragma unroll 10
            for (int k = k0; k < k0 + 20; ++k) {
                const float w = B2_Wo[k * HID + c];
                a0 = fmaf(bbs[0][k], w, a0);
                a1 = fmaf(bbs[1][k], w, a1);
            }
        }
        part[s][0][c] = a0; part[s][1][c] = a1;
    }
    __syncthreads();
    for (int t = threadIdx.x; t < RPB * HID; t += 640) {
        const int r = t / HID, cc = t % HID;
        float acc = B2_bo[cc];
#pragma unroll
        for (int s2 = 0; s2 < 5; ++s2) acc += part[s2][r][cc];
        oos[r][cc] = tanhf(acc);
    }
    __syncthreads();

    // W1-stage: 600 outputs (3 heads x hl/hr x 100 k-cols), K=100 serial.
    // TRANSPOSED write: hlhrT[ho][cc][i0..i0+1] as one float2 (i0 even).
    const int u = threadIdx.x;
    if (u < 600) {
        const int ho = u / HID;
        const int cc = u % HID;
        const int h = ho >> 1, half = ho & 1;
        fp W1 = (h == 0) ? W1r : ((h == 1) ? W1c : W1e);
        fp b1 = (h == 0) ? b1r : ((h == 1) ? b1c : b1e);
        const float bias = half ? 0.f : b1[cc];
        float a0 = bias, a1 = bias;
        const float* Wp = W1 + half * HID * HID;
#pragma unroll 10
        for (int k = 0; k < HID; ++k) {
            const float w = Wp[k * HID + cc];
            a0 = fmaf(oos[0][k], w, a0);
            a1 = fmaf(oos[1][k], w, a1);
        }
        float2 v; v.x = a0; v.y = a1;
        *reinterpret_cast<float2*>(
            &hlhrT[(size_t)ho * (HID * NW) + (size_t)cc * NW + i0]) = v;
    }
}

// ---------------------------------------------------------------------------
// K3 v2: out[h][i][j][:] = relu(hl_i + hr_j) @ W2h + b2h   (f32 output)
// 64x64 tile / block (256 thr), 4x4 micro-tile / thread.
// Panels staged k-major [100][64]: stride-1 LDS writes, per-k reads are
// broadcast (hl) / 2-way (hr) -> conflict-free. 2 b128 LDS reads per k
// feed 64 VALU ops -> VALU-bound.
// ---------------------------------------------------------------------------
__global__ __launch_bounds__(256) void k_pair(
    const float* __restrict__ hlhrT,
    fp W2r, fp b2r, fp W2c, fp b2c, fp W2e, fp b2e,
    float* __restrict__ out) {
    __shared__ __align__(16) float hlS[HID][TJ];
    __shared__ __align__(16) float hrS[HID][TJ];
    __shared__ __align__(16) float w2a[HID];
    __shared__ __align__(16) float w2b[HID];

    const int h  = blockIdx.z;
    const int i0 = blockIdx.y * TJ;
    const int j0 = blockIdx.x * TJ;
    const float* hlg = hlhrT + (size_t)(h * 2 + 0) * (HID * NW);
    const float* hrg = hlhrT + (size_t)(h * 2 + 1) * (HID * NW);

    for (int t = threadIdx.x; t < HID * TJ; t += 256) {
        const int k = t / TJ, j = t % TJ;          // lanes: j stride-1
        hlS[k][j] = hlg[k * NW + i0 + j];          // coalesced 256B reads
        hrS[k][j] = hrg[k * NW + j0 + j];
    }
    fp W2 = (h == 0) ? W2r : ((h == 1) ? W2c : W2e);
    fp b2 = (h == 0) ? b2r : ((h == 1) ? b2c : b2e);
    if (threadIdx.x < HID) {
        w2a[threadIdx.x] = W2[threadIdx.x * 2 + 0];
        w2b[threadIdx.x] = W2[threadIdx.x * 2 + 1];
    }
    __syncthreads();

    const int tx = threadIdx.x & 15;   // j micro-tile (4 cols)
    const int ty = threadIdx.x >> 4;   // i micro-tile (4 rows)
    float acc[4][4][2] = {};

    for (int kb = 0; kb < HID; kb += 4) {
        const float4 wa4 = *(const float4*)&w2a[kb];
        const float4 wb4 = *(const float4*)&w2b[kb];
        const float wav[4] = {wa4.x, wa4.y, wa4.z, wa4.w};
        const float wbv[4] = {wb4.x, wb4.y, wb4.z, wb4.w};
#pragma unroll
        for (int q = 0; q < 4; ++q) {
            const int k = kb + q;
            const float4 a4 = *(const float4*)&hlS[k][ty * 4];
            const float4 r4 = *(const float4*)&hrS[k][tx * 4];
            const float av[4] = {a4.x, a4.y, a4.z, a4.w};
            const float rv[4] = {r4.x, r4.y, r4.z, r4.w};
            const float wa = wav[q], wb = wbv[q];
#pragma unroll
            for (int ii = 0; ii < 4; ++ii)
#pragma unroll
                for (int jj = 0; jj < 4; ++jj) {
                    const float hv = fmaxf(av[ii] + rv[jj], 0.f);
                    acc[ii][jj][0] = fmaf(hv, wa, acc[ii][jj][0]);
                    acc[ii][jj][1] = fmaf(hv, wb, acc[ii][jj][1]);
                }
        }
    }

    const float b20 = b2[0];
    const float b21 = b2[1];
#pragma unroll
    for (int ii = 0; ii < 4; ++ii) {
        const int i = i0 + ty * 4 + ii;
        const size_t rowo = ((size_t)(h * NW + i) * NW + j0 + tx * 4) * 2;
        float4 v0, v1;
        v0.x = acc[ii][0][0] + b20; v0.y = acc[ii][0][1] + b21;
        v0.z = acc[ii][1][0] + b20; v0.w = acc[ii][1][1] + b21;
        v1.x = acc[ii][2][0] + b20; v1.y = acc[ii][2][1] + b21;
        v1.z = acc[ii][3][0] + b20; v1.w = acc[ii][3][1] + b21;
        *reinterpret_cast<float4*>(out + rowo)     = v0;
        *reinterpret_cast<float4*>(out + rowo + 4) = v1;
    }
}

// ---------------------------------------------------------------------------
extern "C" void kernel_launch(void* const* d_in, const int* in_sizes, int n_in,
                              void* d_out, int out_size, void* d_ws,
                              size_t ws_size, hipStream_t stream) {
    int i_vv = -1, i_idx = -1, i_nf = -1, i_AW = -1, i_BW = -1;
    int tens[3] = {-1, -1, -1}; int n10 = 0;   // B2_Wo, B2_Wh, D_W
    int w1s[3]  = {-1, -1, -1}; int n20 = 0;
    int w2s[3]  = {-1, -1, -1}; int n200 = 0;
    int b100[8] = {-1, -1, -1, -1, -1, -1, -1, -1}; int nb = 0;
    int b2s[3]  = {-1, -1, -1}; int nb2 = 0;
    for (int i = 0; i < n_in; ++i) {
        switch (in_sizes[i]) {
            case 236544: i_vv = i; break;
            case 3840:   i_idx = i; break;
            case 768:    i_nf = i; break;
            case 30800:  i_AW = i; break;
            case 60000:  i_BW = i; break;
            case 10000:  if (n10 < 3) tens[n10++] = i; break;
            case 20000:  if (n20 < 3) w1s[n20++] = i; break;
            case 200:    if (n200 < 3) w2s[n200++] = i; break;
            case 100:    if (nb < 8) b100[nb++] = i; break;
            case 2:      if (nb2 < 3) b2s[nb2++] = i; break;
            default: break;
        }
    }
    fp vv          = (fp)d_in[i_vv];
    const int* idx = (const int*)d_in[i_idx];
    const int* nf  = (const int*)d_in[i_nf];
    fp A_W = (fp)d_in[i_AW],      A_b   = (fp)d_in[b100[0]];
    fp B_W = (fp)d_in[i_BW],      B_b   = (fp)d_in[b100[1]];
    fp B2_Wo = (fp)d_in[tens[0]], B2_bo = (fp)d_in[b100[2]];
    fp W1r = (fp)d_in[w1s[0]], b1r = (fp)d_in[b100[5]];
    fp W1c = (fp)d_in[w1s[1]], b1c = (fp)d_in[b100[6]];
    fp W1e = (fp)d_in[w1s[2]], b1e = (fp)d_in[b100[7]];
    fp W2r = (fp)d_in[w2s[0]], b2r = (fp)d_in[b2s[0]];
    fp W2c = (fp)d_in[w2s[1]], b2c = (fp)d_in[b2s[1]];
    fp W2e = (fp)d_in[w2s[2]], b2e = (fp)d_in[b2s[2]];

    float* out = (float*)d_out;

    float* ws    = (float*)d_ws;
    float* uu    = ws;                       // 768*100 f32
    float* hlhrT = ws + NW * HID;            // [6][100][768] f32
    int*   modes = (int*)(ws + NW * HID + 6 * NW * HID);

    k_probe<<<1, 192, 0, stream>>>(nf, idx, modes);
    k_uu<<<NW / RPB, 512, 0, stream>>>(vv, A_W, A_b, uu);
    k_fused<<<NW / RPB, 640, 0, stream>>>(uu, idx, nf, modes, B_W, B_b,
                                          B2_Wo, B2_bo,
                                          W1r, b1r, W1c, b1c, W1e, b1e, hlhrT);
    dim3 grid(NW / TJ, NW / TJ, 3);
    k_pair<<<grid, 256, 0, stream>>>(hlhrT, W2r, b2r, W2c, b2c, W2e, b2e, out);
}

// Round 7
// 55.227 us; speedup vs baseline: 1.1157x; 1.1157x over previous
//
#include <hip/hip_runtime.h>
#include <hip/hip_bf16.h>

// Problem constants (reference: N=768, D_IN=308, H=100, iterations=1)
// Inputs f32, output f32 (verified round 4). hh==0 on the single iteration,
// so B_W[500:600], B2_Wh, D_W/b are dead.
#define NW   768
#define HID  100
#define DIN  308
#define RPB  2          // rows per block in k_uu / k_fused
#define TJ   64         // pair-tile edge

typedef const float* fp;

// ---------------------------------------------------------------------------
// K1: uu = tanh(vv @ A_W + A_b).  RPB rows/block, 512 thr = 4 k-slices x 128
// cols, LDS partial reduce. (proven round 5)
// ---------------------------------------------------------------------------
__global__ __launch_bounds__(512) void k_uu(fp vv, fp A_W, fp A_b,
                                            float* __restrict__ uu) {
    __shared__ float vs[RPB][DIN];
    __shared__ float part[4][RPB][128];
    const int i0 = blockIdx.x * RPB;
    for (int t = threadIdx.x; t < RPB * DIN; t += 512) {
        const int r = t / DIN, k = t % DIN;
        vs[r][k] = vv[(i0 + r) * DIN + k];
    }
    __syncthreads();
    const int c = threadIdx.x & 127;
    const int s = threadIdx.x >> 7;
    float a0 = 0.f, a1 = 0.f;
    if (c < HID) {
        const int k0 = s * 77;
#pragma unroll 11
        for (int k = k0; k < k0 + 77; ++k) {
            const float w = A_W[k * HID + c];
            a0 = fmaf(vs[0][k], w, a0);
            a1 = fmaf(vs[1][k], w, a1);
        }
    }
    part[s][0][c] = a0; part[s][1][c] = a1;
    __syncthreads();
    for (int t = threadIdx.x; t < RPB * HID; t += 512) {
        const int r = t / HID, cc = t % HID;
        float acc = A_b[cc];
#pragma unroll
        for (int s2 = 0; s2 < 4; ++s2) acc += part[s2][r][cc];
        uu[(i0 + r) * HID + cc] = tanhf(acc);
    }
}

// ---------------------------------------------------------------------------
// K2 (fused): inline probe -> gather ww -> bb -> oo -> hl/hr for 3 heads.
// RPB rows/block, 640 thr = 5 k-slices x 128 cols. LDS activations read as
// float4-over-k (4x fewer LDS insts than round 5). Row-major hlhr write
// (reverted from round 6's scattered transpose).
// hlhr layout: [h*2+half][row][100] f32. b1 folded into hl.
// ---------------------------------------------------------------------------
__global__ __launch_bounds__(640) void k_fused(
    const float* __restrict__ uu, const int* __restrict__ indices,
    const int* __restrict__ nf,
    fp B_W, fp B_b, fp B2_Wo, fp B2_bo,
    fp W1r, fp b1r, fp W1c, fp b1c, fp W1e, fp b1e,
    float* __restrict__ hlhr) {
    __shared__ __align__(16) float ww[RPB][5 * HID];
    __shared__ float part[5][RPB][128];
    __shared__ __align__(16) float bbs[RPB][HID];
    __shared__ __align__(16) float oos[RPB][HID];
    __shared__ int flags[6];     // bigNF, badNF, oddNF, evenNF, oddIX, evenIX
    __shared__ int smode[2];

    // ---- inline probe of integer-tensor storage (768 B of each buffer)
    if (threadIdx.x < 6) flags[threadIdx.x] = 0;
    __syncthreads();
    if (threadIdx.x < 192) {
        const int t = threadIdx.x;
        const unsigned vn = (unsigned)nf[t];
        if (vn > 1u) atomicOr(&flags[0], 1);
        if (vn & 0xFEFEFEFEu) atomicOr(&flags[1], 1);
        if ((t & 1) && vn) atomicOr(&flags[2], 1);
        if (!(t & 1) && vn) atomicOr(&flags[3], 1);
        const unsigned vi = (unsigned)indices[t];
        if ((t & 1) && vi) atomicOr(&flags[4], 1);
        if (!(t & 1) && vi) atomicOr(&flags[5], 1);
    }
    __syncthreads();
    if (threadIdx.x == 0) {
        int m = 0;
        if (!flags[1] && flags[0]) m = 1;            // packed uint8 bools
        else if (!flags[2] && flags[3]) m = 2;       // int64 per element
        smode[0] = m;
        smode[1] = (!flags[4] && flags[5]) ? 1 : 0;  // idx int64?
    }
    __syncthreads();
    const int mnf = smode[0], midx = smode[1];

    const int i0 = blockIdx.x * RPB;
    // ---- gather 5 neighbor uu rows per block-row (zeroed if not_found)
    for (int t = threadIdx.x; t < RPB * 5 * HID; t += 640) {
        const int r = t / (5 * HID), u = t % (5 * HID);
        const int i = i0 + r;
        const bool notf = (mnf == 1) ? (((const unsigned char*)nf)[i] != 0)
                        : (mnf == 2) ? (nf[2 * i] != 0)
                                     : (nf[i] != 0);
        const int q = u / HID, cc = u % HID;
        int j = midx ? indices[2 * (i * 5 + q)] : indices[i * 5 + q];
        j = (j < 0) ? 0 : ((j >= NW) ? NW - 1 : j);
        ww[r][u] = notf ? 0.f : uu[j * HID + cc];
    }
    __syncthreads();

    const int c = threadIdx.x % 128;
    const int s = threadIdx.x / 128;        // 0..4

    // ---- B-stage: k-slice of 100, float4 LDS reads over k
    {
        float a0 = 0.f, a1 = 0.f;
        if (c < HID) {
            const int k0 = s * 100;
#pragma unroll 5
            for (int k = k0; k < k0 + 100; k += 4) {
                const float4 w0 = *(const float4*)&ww[0][k];
                const float4 w1 = *(const float4*)&ww[1][k];
                const float b0 = B_W[(k + 0) * HID + c];
                const float b1v = B_W[(k + 1) * HID + c];
                const float b2v = B_W[(k + 2) * HID + c];
                const float b3 = B_W[(k + 3) * HID + c];
                a0 = fmaf(w0.x, b0, a0); a1 = fmaf(w1.x, b0, a1);
                a0 = fmaf(w0.y, b1v, a0); a1 = fmaf(w1.y, b1v, a1);
                a0 = fmaf(w0.z, b2v, a0); a1 = fmaf(w1.z, b2v, a1);
                a0 = fmaf(w0.w, b3, a0); a1 = fmaf(w1.w, b3, a1);
            }
        }
        part[s][0][c] = a0; part[s][1][c] = a1;
    }
    __syncthreads();
    for (int t = threadIdx.x; t < RPB * HID; t += 640) {
        const int r = t / HID, cc = t % HID;
        float acc = B_b[cc];
#pragma unroll
        for (int s2 = 0; s2 < 5; ++s2) acc += part[s2][r][cc];
        bbs[r][cc] = tanhf(acc);
    }
    __syncthreads();

    // ---- oo-stage: k-slice of 20
    {
        float a0 = 0.f, a1 = 0.f;
        if (c < HID) {
            const int k0 = s * 20;
#pragma unroll 5
            for (int k = k0; k < k0 + 20; k += 4) {
                const float4 w0 = *(const float4*)&bbs[0][k];
                const float4 w1 = *(const float4*)&bbs[1][k];
                const float b0 = B2_Wo[(k + 0) * HID + c];
                const float b1v = B2_Wo[(k + 1) * HID + c];
                const float b2v = B2_Wo[(k + 2) * HID + c];
                const float b3 = B2_Wo[(k + 3) * HID + c];
                a0 = fmaf(w0.x, b0, a0); a1 = fmaf(w1.x, b0, a1);
                a0 = fmaf(w0.y, b1v, a0); a1 = fmaf(w1.y, b1v, a1);
                a0 = fmaf(w0.z, b2v, a0); a1 = fmaf(w1.z, b2v, a1);
                a0 = fmaf(w0.w, b3, a0); a1 = fmaf(w1.w, b3, a1);
            }
        }
        part[s][0][c] = a0; part[s][1][c] = a1;
    }
    __syncthreads();
    for (int t = threadIdx.x; t < RPB * HID; t += 640) {
        const int r = t / HID, cc = t % HID;
        float acc = B2_bo[cc];
#pragma unroll
        for (int s2 = 0; s2 < 5; ++s2) acc += part[s2][r][cc];
        oos[r][cc] = tanhf(acc);
    }
    __syncthreads();

    // ---- W1-stage: 600 outputs, K=100 with float4 LDS reads; row-major write
    const int u = threadIdx.x;
    if (u < 600) {
        const int ho = u / HID;
        const int cc = u % HID;
        const int h = ho >> 1, half = ho & 1;
        fp W1 = (h == 0) ? W1r : ((h == 1) ? W1c : W1e);
        fp b1 = (h == 0) ? b1r : ((h == 1) ? b1c : b1e);
        const float bias = half ? 0.f : b1[cc];
        float a0 = bias, a1 = bias;
        const float* Wp = W1 + half * HID * HID;
#pragma unroll 5
        for (int k = 0; k < HID; k += 4) {
            const float4 o0 = *(const float4*)&oos[0][k];
            const float4 o1 = *(const float4*)&oos[1][k];
            const float b0 = Wp[(k + 0) * HID + cc];
            const float b1v = Wp[(k + 1) * HID + cc];
            const float b2v = Wp[(k + 2) * HID + cc];
            const float b3 = Wp[(k + 3) * HID + cc];
            a0 = fmaf(o0.x, b0, a0); a1 = fmaf(o1.x, b0, a1);
            a0 = fmaf(o0.y, b1v, a0); a1 = fmaf(o1.y, b1v, a1);
            a0 = fmaf(o0.z, b2v, a0); a1 = fmaf(o1.z, b2v, a1);
            a0 = fmaf(o0.w, b3, a0); a1 = fmaf(o1.w, b3, a1);
        }
        hlhr[(size_t)ho * (NW * HID) + (size_t)(i0 + 0) * HID + cc] = a0;
        hlhr[(size_t)ho * (NW * HID) + (size_t)(i0 + 1) * HID + cc] = a1;
    }
}

// ---------------------------------------------------------------------------
// K3 v3: out[h][i][j][:] = relu(hl_i + hr_j) @ W2h + b2h   (f32 output)
// 64x64 tile / block (256 thr), 4x4 micro-tile / thread.
// LDS k-major [100][64] built by transpose-staging from row-major hlhr with
// XOR swizzle r^((k&7)<<2): staging writes 8-way (one-off), all compute
// reads conflict-free aligned b128. Interleaved-channel fmaf pairs.
// ---------------------------------------------------------------------------
__global__ __launch_bounds__(256) void k_pair(
    const float* __restrict__ hlhr,
    fp W2r, fp b2r, fp W2c, fp b2c, fp W2e, fp b2e,
    float* __restrict__ out) {
    __shared__ __align__(16) float hlS[HID][TJ];
    __shared__ __align__(16) float hrS[HID][TJ];
    __shared__ __align__(16) float2 w2s[HID];

    const int h  = blockIdx.z;
    const int i0 = blockIdx.y * TJ;
    const int j0 = blockIdx.x * TJ;
    const float* hl = hlhr + (size_t)(h * 2 + 0) * (NW * HID) + (size_t)i0 * HID;
    const float* hr = hlhr + (size_t)(h * 2 + 1) * (NW * HID) + (size_t)j0 * HID;

    // transpose-stage rows->k-major with swizzled col
    for (int t = threadIdx.x; t < TJ * HID; t += 256) {
        const int r = t / HID, k = t % HID;
        const int rs = r ^ ((k & 7) << 2);
        hlS[k][rs] = hl[t];
        hrS[k][rs] = hr[t];
    }
    fp W2 = (h == 0) ? W2r : ((h == 1) ? W2c : W2e);
    fp b2 = (h == 0) ? b2r : ((h == 1) ? b2c : b2e);
    if (threadIdx.x < HID) {
        w2s[threadIdx.x] = make_float2(W2[2 * threadIdx.x], W2[2 * threadIdx.x + 1]);
    }
    __syncthreads();

    const int tx = threadIdx.x & 15;   // j micro-tile (4 cols)
    const int ty = threadIdx.x >> 4;   // i micro-tile (4 rows)
    float2 acc[4][4];
#pragma unroll
    for (int ii = 0; ii < 4; ++ii)
#pragma unroll
        for (int jj = 0; jj < 4; ++jj) acc[ii][jj] = make_float2(0.f, 0.f);

    for (int k = 0; k < HID; ++k) {
        const int sw = (k & 7) << 2;
        const float4 a4 = *(const float4*)&hlS[k][(ty * 4) ^ sw];
        const float4 r4 = *(const float4*)&hrS[k][(tx * 4) ^ sw];
        const float2 w2 = w2s[k];
        const float av[4] = {a4.x, a4.y, a4.z, a4.w};
        const float rv[4] = {r4.x, r4.y, r4.z, r4.w};
#pragma unroll
        for (int ii = 0; ii < 4; ++ii)
#pragma unroll
            for (int jj = 0; jj < 4; ++jj) {
                const float hv = fmaxf(av[ii] + rv[jj], 0.f);
                acc[ii][jj].x = fmaf(hv, w2.x, acc[ii][jj].x);
                acc[ii][jj].y = fmaf(hv, w2.y, acc[ii][jj].y);
            }
    }

    const float b20 = b2[0];
    const float b21 = b2[1];
#pragma unroll
    for (int ii = 0; ii < 4; ++ii) {
        const int i = i0 + ty * 4 + ii;
        const size_t rowo = ((size_t)(h * NW + i) * NW + j0 + tx * 4) * 2;
        float4 v0, v1;
        v0.x = acc[ii][0].x + b20; v0.y = acc[ii][0].y + b21;
        v0.z = acc[ii][1].x + b20; v0.w = acc[ii][1].y + b21;
        v1.x = acc[ii][2].x + b20; v1.y = acc[ii][2].y + b21;
        v1.z = acc[ii][3].x + b20; v1.w = acc[ii][3].y + b21;
        *reinterpret_cast<float4*>(out + rowo)     = v0;
        *reinterpret_cast<float4*>(out + rowo + 4) = v1;
    }
}

// ---------------------------------------------------------------------------
extern "C" void kernel_launch(void* const* d_in, const int* in_sizes, int n_in,
                              void* d_out, int out_size, void* d_ws,
                              size_t ws_size, hipStream_t stream) {
    int i_vv = -1, i_idx = -1, i_nf = -1, i_AW = -1, i_BW = -1;
    int tens[3] = {-1, -1, -1}; int n10 = 0;   // B2_Wo, B2_Wh, D_W
    int w1s[3]  = {-1, -1, -1}; int n20 = 0;
    int w2s_[3] = {-1, -1, -1}; int n200 = 0;
    int b100[8] = {-1, -1, -1, -1, -1, -1, -1, -1}; int nb = 0;
    int b2s[3]  = {-1, -1, -1}; int nb2 = 0;
    for (int i = 0; i < n_in; ++i) {
        switch (in_sizes[i]) {
            case 236544: i_vv = i; break;
            case 3840:   i_idx = i; break;
            case 768:    i_nf = i; break;
            case 30800:  i_AW = i; break;
            case 60000:  i_BW = i; break;
            case 10000:  if (n10 < 3) tens[n10++] = i; break;
            case 20000:  if (n20 < 3) w1s[n20++] = i; break;
            case 200:    if (n200 < 3) w2s_[n200++] = i; break;
            case 100:    if (nb < 8) b100[nb++] = i; break;
            case 2:      if (nb2 < 3) b2s[nb2++] = i; break;
            default: break;  // num_words (size 1)
        }
    }
    fp vv          = (fp)d_in[i_vv];
    const int* idx = (const int*)d_in[i_idx];
    const int* nf  = (const int*)d_in[i_nf];
    fp A_W = (fp)d_in[i_AW],      A_b   = (fp)d_in[b100[0]];
    fp B_W = (fp)d_in[i_BW],      B_b   = (fp)d_in[b100[1]];
    fp B2_Wo = (fp)d_in[tens[0]], B2_bo = (fp)d_in[b100[2]];
    fp W1r = (fp)d_in[w1s[0]], b1r = (fp)d_in[b100[5]];
    fp W1c = (fp)d_in[w1s[1]], b1c = (fp)d_in[b100[6]];
    fp W1e = (fp)d_in[w1s[2]], b1e = (fp)d_in[b100[7]];
    fp W2r = (fp)d_in[w2s_[0]], b2r = (fp)d_in[b2s[0]];
    fp W2c = (fp)d_in[w2s_[1]], b2c = (fp)d_in[b2s[1]];
    fp W2e = (fp)d_in[w2s_[2]], b2e = (fp)d_in[b2s[2]];

    float* out = (float*)d_out;

    float* ws   = (float*)d_ws;
    float* uu   = ws;                       // 768*100 f32
    float* hlhr = ws + NW * HID;            // [6][768][100] f32

    k_uu<<<NW / RPB, 512, 0, stream>>>(vv, A_W, A_b, uu);
    k_fused<<<NW / RPB, 640, 0, stream>>>(uu, idx, nf, B_W, B_b,
                                          B2_Wo, B2_bo,
                                          W1r, b1r, W1c, b1c, W1e, b1e, hlhr);
    dim3 grid(NW / TJ, NW / TJ, 3);
    k_pair<<<grid, 256, 0, stream>>>(hlhr, W2r, b2r, W2c, b2c, W2e, b2e, out);
}